// Round 1
// baseline (616.033 us; speedup 1.0000x reference)
//
#include <hip/hip_runtime.h>

// Problem constants (B=4, V=1024, L=2048, H=2048, TEMP=1, EPS=1e-12)
#define H_ 2048

typedef __attribute__((ext_vector_type(8))) short short8;
typedef __attribute__((ext_vector_type(4))) float f32x4;
typedef __attribute__((ext_vector_type(4))) unsigned int u32x4;

__device__ __forceinline__ unsigned short f2bf(float f) {
  unsigned int u = __builtin_bit_cast(unsigned int, f);
  u += 0x7FFFu + ((u >> 16) & 1u);  // RTNE
  return (unsigned short)(u >> 16);
}
__device__ __forceinline__ float bf2f(unsigned short h) {
  unsigned int u = ((unsigned int)h) << 16;
  return __builtin_bit_cast(float, u);
}
__device__ __forceinline__ unsigned int pk2(float a, float b) {
  return (unsigned int)f2bf(a) | ((unsigned int)f2bf(b) << 16);
}

#define GLDS16(gp, lp)                                                 \
  __builtin_amdgcn_global_load_lds(                                    \
      (const __attribute__((address_space(1))) void*)(gp),             \
      (__attribute__((address_space(3))) void*)(lp), 16, 0, 0)

// ---------------------------------------------------------------------------
// prep: per-row 1/max(||row||,eps) + raw bf16 copy; rows >= validRows -> zeros
// ---------------------------------------------------------------------------
__global__ __launch_bounds__(256) void prep_rows(
    const float* __restrict__ in, long sIn,
    unsigned short* __restrict__ outBf, long sOut,
    float* __restrict__ rnorm, int validRows) {
  const int tid = threadIdx.x;
  const int r = blockIdx.x, b = blockIdx.y;
  unsigned short* orow = outBf + (long)b * sOut + (long)r * H_ + tid * 8;
  if (r >= validRows) {
    *(u32x4*)orow = (u32x4){0u, 0u, 0u, 0u};
    if (tid == 0) rnorm[b * H_ + r] = 0.f;
    return;
  }
  const float* row = in + (long)b * sIn + (long)r * H_ + tid * 8;
  f32x4 x0 = *(const f32x4*)row;
  f32x4 x1 = *(const f32x4*)(row + 4);
  float ss = x0[0]*x0[0] + x0[1]*x0[1] + x0[2]*x0[2] + x0[3]*x0[3]
           + x1[0]*x1[0] + x1[1]*x1[1] + x1[2]*x1[2] + x1[3]*x1[3];
#pragma unroll
  for (int o = 32; o; o >>= 1) ss += __shfl_xor(ss, o, 64);
  __shared__ float red[4];
  if ((tid & 63) == 0) red[tid >> 6] = ss;
  __syncthreads();
  if (tid == 0) {
    float tot = red[0] + red[1] + red[2] + red[3];
    rnorm[b * H_ + r] = 1.f / fmaxf(sqrtf(tot), 1e-12f);
  }
  u32x4 o;
  o[0] = pk2(x0[0], x0[1]); o[1] = pk2(x0[2], x0[3]);
  o[2] = pk2(x1[0], x1[1]); o[3] = pk2(x1[2], x1[3]);
  *(u32x4*)orow = o;
}

// ---------------------------------------------------------------------------
// column sums (means over padded length 2048) — two stage for parallelism
// ---------------------------------------------------------------------------
__global__ __launch_bounds__(256) void col_sum_part(
    const float* __restrict__ vis, const float* __restrict__ lang,
    float* __restrict__ part) {
  // grid (8, 8, 8): x=h-chunk, y=row-chunk(256), z = b*2+which (which: 0=vis,1=lang)
  const int h = blockIdx.x * 256 + threadIdx.x;
  const int y = blockIdx.y;
  const int which = blockIdx.z & 1;
  const int b = blockIdx.z >> 1;
  const int rows = which ? 2048 : 1024;
  const int r0 = y * 256;
  float s = 0.f;
  if (r0 < rows) {
    const float* p = (which ? lang + (long)b * (2048L * 2048)
                            : vis + (long)b * (1024L * 2048)) + (long)r0 * H_ + h;
#pragma unroll 4
    for (int i = 0; i < 256; ++i) s += p[(long)i * H_];
  }
  part[(((long)which * 4 + b) * 8 + y) * H_ + h] = s;
}

__global__ __launch_bounds__(256) void col_sum_final(
    const float* __restrict__ part, float* __restrict__ vavg,
    float* __restrict__ lavg) {
  // grid (8, 4, 2)
  const int h = blockIdx.x * 256 + threadIdx.x;
  const int b = blockIdx.y;
  const int which = blockIdx.z;
  const float* p = part + (((long)which * 4 + b) * 8) * H_ + h;
  float s = 0.f;
#pragma unroll
  for (int y = 0; y < 8; ++y) s += p[y * H_];
  (which ? lavg : vavg)[b * H_ + h] = s * (1.f / 2048.f);
}

// ---------------------------------------------------------------------------
// bias GEMV: bias[b,h] = sum_{d<2048} avg[b,d] * W[h*4096 + d]   (4 batches/wave)
// ---------------------------------------------------------------------------
__global__ __launch_bounds__(256) void bias_gemv(
    const float* __restrict__ W, const float* __restrict__ avg,
    float* __restrict__ bias) {
  const int lane = threadIdx.x & 63;
  const int wv = threadIdx.x >> 6;
  const int h = blockIdx.x * 4 + wv;
  const float* wrow = W + (long)h * 4096;
  float a0 = 0.f, a1 = 0.f, a2 = 0.f, a3 = 0.f;
#pragma unroll
  for (int i = 0; i < 8; ++i) {
    const int d = i * 256 + lane * 4;
    f32x4 w4 = *(const f32x4*)(wrow + d);
    f32x4 v0 = *(const f32x4*)(avg + 0 * H_ + d);
    f32x4 v1 = *(const f32x4*)(avg + 1 * H_ + d);
    f32x4 v2 = *(const f32x4*)(avg + 2 * H_ + d);
    f32x4 v3 = *(const f32x4*)(avg + 3 * H_ + d);
    a0 += w4[0]*v0[0] + w4[1]*v0[1] + w4[2]*v0[2] + w4[3]*v0[3];
    a1 += w4[0]*v1[0] + w4[1]*v1[1] + w4[2]*v1[2] + w4[3]*v1[3];
    a2 += w4[0]*v2[0] + w4[1]*v2[1] + w4[2]*v2[2] + w4[3]*v2[3];
    a3 += w4[0]*v3[0] + w4[1]*v3[1] + w4[2]*v3[2] + w4[3]*v3[3];
  }
#pragma unroll
  for (int o = 32; o; o >>= 1) {
    a0 += __shfl_xor(a0, o, 64);
    a1 += __shfl_xor(a1, o, 64);
    a2 += __shfl_xor(a2, o, 64);
    a3 += __shfl_xor(a3, o, 64);
  }
  if (lane == 0) {
    bias[0 * H_ + h] = a0; bias[1 * H_ + h] = a1;
    bias[2 * H_ + h] = a2; bias[3 * H_ + h] = a3;
  }
}

// ---------------------------------------------------------------------------
// transpose lang (f32 [b][l][h]) -> lang_T (bf16 [b][h][l])
// ---------------------------------------------------------------------------
__global__ __launch_bounds__(256) void transpose_bf(
    const float* __restrict__ in, unsigned short* __restrict__ out) {
  __shared__ unsigned short tle[64][72];
  const int b = blockIdx.z;
  const int l0 = blockIdx.y * 64, h0 = blockIdx.x * 64;
  const float* inb = in + (long)b * (2048L * 2048);
  unsigned short* outb = out + (long)b * (2048L * 2048);
#pragma unroll
  for (int i = 0; i < 16; ++i) {
    const int idx = i * 256 + threadIdx.x;
    const int r = idx >> 6, c = idx & 63;
    tle[r][c] = f2bf(inb[(long)(l0 + r) * H_ + h0 + c]);
  }
  __syncthreads();
#pragma unroll
  for (int i = 0; i < 16; ++i) {
    const int idx = i * 256 + threadIdx.x;
    const int r = idx >> 6, c = idx & 63;  // r = h-local, c = l-local
    outb[(long)(h0 + r) * H_ + l0 + c] = tle[c][r];
  }
}

// ---------------------------------------------------------------------------
// extract W[:, 2048:4096] as bf16 row-major [h][k]
// ---------------------------------------------------------------------------
__global__ __launch_bounds__(256) void extract_whi(
    const float* __restrict__ Wvl, const float* __restrict__ Wlv,
    unsigned short* __restrict__ WvlHi, unsigned short* __restrict__ WlvHi) {
  const int h = blockIdx.x;
  const int which = blockIdx.y;
  const float* src = (which ? Wlv : Wvl) + (long)h * 4096 + 2048 + threadIdx.x * 8;
  unsigned short* dst = (which ? WlvHi : WvlHi) + (long)h * H_ + threadIdx.x * 8;
  f32x4 x0 = *(const f32x4*)src;
  f32x4 x1 = *(const f32x4*)(src + 4);
  u32x4 o;
  o[0] = pk2(x0[0], x0[1]); o[1] = pk2(x0[2], x0[3]);
  o[2] = pk2(x1[0], x1[1]); o[3] = pk2(x1[2], x1[3]);
  *(u32x4*)dst = o;
}

// ---------------------------------------------------------------------------
// row softmax in place over bf16 [rows][2048]
// ---------------------------------------------------------------------------
__global__ __launch_bounds__(256) void softmax_rows(unsigned short* __restrict__ S) {
  const int tid = threadIdx.x;
  const int lane = tid & 63, wv = tid >> 6;
  unsigned short* rowp = S + (long)blockIdx.x * H_ + tid * 8;
  u32x4 raw = *(const u32x4*)rowp;
  float v[8];
#pragma unroll
  for (int i = 0; i < 4; ++i) {
    v[2 * i]     = bf2f((unsigned short)(raw[i] & 0xFFFFu));
    v[2 * i + 1] = bf2f((unsigned short)(raw[i] >> 16));
  }
  float mx = v[0];
#pragma unroll
  for (int i = 1; i < 8; ++i) mx = fmaxf(mx, v[i]);
#pragma unroll
  for (int o = 32; o; o >>= 1) mx = fmaxf(mx, __shfl_xor(mx, o, 64));
  __shared__ float red[4];
  if (lane == 0) red[wv] = mx;
  __syncthreads();
  const float MX = fmaxf(fmaxf(red[0], red[1]), fmaxf(red[2], red[3]));
  float p[8], s = 0.f;
#pragma unroll
  for (int i = 0; i < 8; ++i) { p[i] = __expf(v[i] - MX); s += p[i]; }
#pragma unroll
  for (int o = 32; o; o >>= 1) s += __shfl_xor(s, o, 64);
  __syncthreads();
  if (lane == 0) red[wv] = s;
  __syncthreads();
  const float inv = 1.f / (red[0] + red[1] + red[2] + red[3]);
  u32x4 o;
#pragma unroll
  for (int i = 0; i < 4; ++i) o[i] = pk2(p[2 * i] * inv, p[2 * i + 1] * inv);
  *(u32x4*)rowp = o;
}

// ---------------------------------------------------------------------------
// NT GEMM (C = A * B^T), A: M x 2048 bf16 row-major, B: 2048 x 2048 bf16
// row-major (N-major, K-contiguous). 128x128 tile, BK=32, 4 waves, m97-style
// global_load_lds staging. MODE 0: scores (scale rv*rl -> bf16);
// MODE 1: f32 write (fused); MODE 2: sigmoid-gate epilogue.
// ---------------------------------------------------------------------------
struct EpArgs {
  unsigned short* Sout; const float* rv; const float* rl;  // MODE 0
  float* Fout;                                             // MODE 1
  const float* resid; const float* fusedIn; const float* bias; float* Oout;
  long sResid, sFused, sOut;                               // MODE 2
};

template <int MODE>
__global__ __launch_bounds__(256) void gemm_nt(
    const unsigned short* __restrict__ A, long sA,
    const unsigned short* __restrict__ B, long sB, EpArgs ep) {
  const int tid = threadIdx.x;
  const int lane = tid & 63;
  const int wave = tid >> 6;
  const int b = blockIdx.z;
  const int bm = blockIdx.y << 7;
  const int bn = blockIdx.x << 7;

  __shared__ unsigned short As[128 * 32];
  __shared__ unsigned short Bs[128 * 32];

  const unsigned short* Ab = A + (long)b * sA;
  const unsigned short* Bb = B + (long)b * sB;
  const int r0 = tid >> 2;
  const int kc = (tid & 3) << 3;
  const unsigned short* gA = Ab + (long)(bm + r0) * H_ + kc;
  const unsigned short* gB = Bb + (long)(bn + r0) * H_ + kc;

  char* ldsA0 = (char*)As + wave * 1024;
  char* ldsA1 = (char*)As + 4096 + wave * 1024;
  char* ldsB0 = (char*)Bs + wave * 1024;
  char* ldsB1 = (char*)Bs + 4096 + wave * 1024;

  f32x4 acc[4][4];
#pragma unroll
  for (int m = 0; m < 4; ++m)
#pragma unroll
    for (int n = 0; n < 4; ++n) acc[m][n] = (f32x4){0.f, 0.f, 0.f, 0.f};

  const int wr = (wave >> 1) << 6;
  const int wc = (wave & 1) << 6;
  const int row16 = lane & 15;
  const int kg = lane >> 4;

#define STAGE_(kt)                                        \
  do {                                                    \
    const unsigned short* a_ = gA + (kt) * 32;            \
    const unsigned short* b_ = gB + (kt) * 32;            \
    GLDS16(a_, ldsA0); GLDS16(a_ + 64 * H_, ldsA1);       \
    GLDS16(b_, ldsB0); GLDS16(b_ + 64 * H_, ldsB1);       \
  } while (0)

  STAGE_(0);
  for (int kt = 0; kt < H_ / 32; ++kt) {
    __syncthreads();  // staging complete (compiler drains vmcnt before barrier)
    short8 af[4], bfv[4];
#pragma unroll
    for (int m = 0; m < 4; ++m)
      af[m] = *(const short8*)(As + (wr + m * 16 + row16) * 32 + kg * 8);
#pragma unroll
    for (int n = 0; n < 4; ++n)
      bfv[n] = *(const short8*)(Bs + (wc + n * 16 + row16) * 32 + kg * 8);
#pragma unroll
    for (int m = 0; m < 4; ++m)
#pragma unroll
      for (int n = 0; n < 4; ++n)
        acc[m][n] = __builtin_amdgcn_mfma_f32_16x16x32_bf16(af[m], bfv[n],
                                                            acc[m][n], 0, 0, 0);
    __syncthreads();  // all LDS reads done before restaging
    if (kt + 1 < H_ / 32) STAGE_(kt + 1);
  }

  // C/D layout: col = lane&15, row = (lane>>4)*4 + j   [verified m89/m91]
  const int cr0 = bm + wr + kg * 4;
  const int cc0 = bn + wc + row16;

  if (MODE == 0) {
    float rvv[4][4], rlv[4];
#pragma unroll
    for (int m = 0; m < 4; ++m)
#pragma unroll
      for (int j = 0; j < 4; ++j) rvv[m][j] = ep.rv[b * H_ + cr0 + m * 16 + j];
#pragma unroll
    for (int n = 0; n < 4; ++n) rlv[n] = ep.rl[b * H_ + cc0 + n * 16];
    unsigned short* Sb = ep.Sout + (long)b * (H_ * (long)H_);
#pragma unroll
    for (int m = 0; m < 4; ++m)
#pragma unroll
      for (int n = 0; n < 4; ++n)
#pragma unroll
        for (int j = 0; j < 4; ++j) {
          const long idx = (long)(cr0 + m * 16 + j) * H_ + cc0 + n * 16;
          Sb[idx] = f2bf(acc[m][n][j] * rvv[m][j] * rlv[n]);
        }
  } else if (MODE == 1) {
    float* Fb = ep.Fout + (long)b * (H_ * (long)H_);
#pragma unroll
    for (int m = 0; m < 4; ++m)
#pragma unroll
      for (int n = 0; n < 4; ++n)
#pragma unroll
        for (int j = 0; j < 4; ++j) {
          const long idx = (long)(cr0 + m * 16 + j) * H_ + cc0 + n * 16;
          Fb[idx] = acc[m][n][j];
        }
  } else {
    const float* Rb = ep.resid + (long)b * ep.sResid;
    const float* Fb = ep.fusedIn + (long)b * ep.sFused;
    float* Ob = ep.Oout + (long)b * ep.sOut;
    float bv[4];
#pragma unroll
    for (int n = 0; n < 4; ++n) bv[n] = ep.bias[b * H_ + cc0 + n * 16];
#pragma unroll
    for (int m = 0; m < 4; ++m)
#pragma unroll
      for (int n = 0; n < 4; ++n)
#pragma unroll
        for (int j = 0; j < 4; ++j) {
          const long idx = (long)(cr0 + m * 16 + j) * H_ + cc0 + n * 16;
          const float x = acc[m][n][j] + bv[n];
          const float g = 1.f / (1.f + __expf(-x));
          Ob[idx] = Rb[idx] + Fb[idx] * g;
        }
  }
#undef STAGE_
}

// ---------------------------------------------------------------------------
extern "C" void kernel_launch(void* const* d_in, const int* in_sizes, int n_in,
                              void* d_out, int out_size, void* d_ws,
                              size_t ws_size, hipStream_t stream) {
  (void)in_sizes; (void)n_in; (void)out_size; (void)ws_size;
  const float* vis = (const float*)d_in[0];   // [4,1024,2048]
  const float* lang = (const float*)d_in[1];  // [4,2048,2048]
  const float* Wvl = (const float*)d_in[2];   // [2048,4096]
  const float* Wlv = (const float*)d_in[3];   // [2048,4096]

  // d_out regions: fused | vision_output | language_output
  float* out = (float*)d_out;
  float* fused = out;                      // 16,777,216 f32
  float* vis_out = out + 16777216;         //  8,388,608 f32
  float* lang_out = out + 25165824;        // 16,777,216 f32
  // scratch reuse of not-yet-final output regions:
  unsigned short* S = (unsigned short*)lang_out;     // scores/P bf16 (33.5MB of 67MB)
  unsigned short* langT = (unsigned short*)vis_out;  // lang^T bf16 (33.5MB exact)

  // workspace layout
  char* w = (char*)d_ws;
  unsigned short* vis_bf = (unsigned short*)w;               // [4,2048,2048] bf16 (padded)
  unsigned short* lang_bf = (unsigned short*)(w + 33554432); // [4,2048,2048] bf16
  unsigned short* WvlHi = (unsigned short*)(w + 67108864);   // [2048,2048] bf16
  unsigned short* WlvHi = (unsigned short*)(w + 75497472);   // [2048,2048] bf16
  float* rv      = (float*)(w + 83886080);
  float* rl      = (float*)(w + 83918848);
  float* vavg    = (float*)(w + 83951616);
  float* lavg    = (float*)(w + 83984384);
  float* bias_vl = (float*)(w + 84017152);
  float* bias_lv = (float*)(w + 84049920);
  float* part    = (float*)(w + 84082688);  // 512KB partial col sums

  const long sV = 1024L * 2048, sL = 2048L * 2048, sP = 2048L * 2048;

  prep_rows<<<dim3(2048, 4), 256, 0, stream>>>(vis, sV, vis_bf, sP, rv, 1024);
  prep_rows<<<dim3(2048, 4), 256, 0, stream>>>(lang, sL, lang_bf, sP, rl, 2048);
  col_sum_part<<<dim3(8, 8, 8), 256, 0, stream>>>(vis, lang, part);
  col_sum_final<<<dim3(8, 4, 2), 256, 0, stream>>>(part, vavg, lavg);
  bias_gemv<<<512, 256, 0, stream>>>(Wvl, vavg, bias_vl);
  bias_gemv<<<512, 256, 0, stream>>>(Wlv, lavg, bias_lv);
  transpose_bf<<<dim3(32, 32, 4), 256, 0, stream>>>(lang, langT);
  extract_whi<<<dim3(2048, 2), 256, 0, stream>>>(Wvl, Wlv, WvlHi, WlvHi);

  // GEMM1: scores S[b,v,l] = (vis . lang) * rv * rl  -> bf16
  EpArgs e1 = {};
  e1.Sout = S; e1.rv = rv; e1.rl = rl;
  gemm_nt<0><<<dim3(16, 16, 4), 256, 0, stream>>>(vis_bf, sP, lang_bf, sP, e1);

  softmax_rows<<<8192, 256, 0, stream>>>(S);

  // GEMM2: fused[b,v,h] = P . lang  (B = lang^T, NT form) -> f32
  EpArgs e2 = {};
  e2.Fout = fused;
  gemm_nt<1><<<dim3(16, 16, 4), 256, 0, stream>>>(S, sP, langT, sP, e2);

  // GEMM3: language_output = lang + fused * sigmoid(lang.WvlHi^T + bias_vl)
  EpArgs e3 = {};
  e3.resid = lang; e3.sResid = sL;
  e3.fusedIn = fused; e3.sFused = sP;
  e3.bias = bias_vl; e3.Oout = lang_out; e3.sOut = sL;
  gemm_nt<2><<<dim3(16, 16, 4), 256, 0, stream>>>(lang_bf, sP, WvlHi, 0L, e3);

  // GEMM4: vision_output = vis + fused[:, :1024] * sigmoid(vis.WlvHi^T + bias_lv)
  EpArgs e4 = {};
  e4.resid = vis; e4.sResid = sV;
  e4.fusedIn = fused; e4.sFused = sP;
  e4.bias = bias_lv; e4.Oout = vis_out; e4.sOut = sV;
  gemm_nt<2><<<dim3(16, 8, 4), 256, 0, stream>>>(vis_bf, sP, WlvHi, 0L, e4);
}

// Round 2
// 577.754 us; speedup vs baseline: 1.0663x; 1.0663x over previous
//
#include <hip/hip_runtime.h>

// Problem constants (B=4, V=1024, L=2048, H=2048, TEMP=1, EPS=1e-12)
#define H_ 2048

typedef __attribute__((ext_vector_type(8))) short short8;
typedef __attribute__((ext_vector_type(4))) float f32x4;
typedef __attribute__((ext_vector_type(4))) unsigned int u32x4;

__device__ __forceinline__ unsigned short f2bf(float f) {
  unsigned int u = __builtin_bit_cast(unsigned int, f);
  u += 0x7FFFu + ((u >> 16) & 1u);  // RTNE
  return (unsigned short)(u >> 16);
}
__device__ __forceinline__ float bf2f(unsigned short h) {
  unsigned int u = ((unsigned int)h) << 16;
  return __builtin_bit_cast(float, u);
}
__device__ __forceinline__ unsigned int pk2(float a, float b) {
  return (unsigned int)f2bf(a) | ((unsigned int)f2bf(b) << 16);
}

#define GLDS16(gp, lp)                                                 \
  __builtin_amdgcn_global_load_lds(                                    \
      (const __attribute__((address_space(1))) void*)(gp),             \
      (__attribute__((address_space(3))) void*)(lp), 16, 0, 0)

// ---------------------------------------------------------------------------
// prep: per-row 1/max(||row||,eps) + raw bf16 copy; rows >= validRows -> zeros
// ---------------------------------------------------------------------------
__global__ __launch_bounds__(256) void prep_rows(
    const float* __restrict__ in, long sIn,
    unsigned short* __restrict__ outBf, long sOut,
    float* __restrict__ rnorm, int validRows) {
  const int tid = threadIdx.x;
  const int r = blockIdx.x, b = blockIdx.y;
  unsigned short* orow = outBf + (long)b * sOut + (long)r * H_ + tid * 8;
  if (r >= validRows) {
    *(u32x4*)orow = (u32x4){0u, 0u, 0u, 0u};
    if (tid == 0) rnorm[b * H_ + r] = 0.f;
    return;
  }
  const float* row = in + (long)b * sIn + (long)r * H_ + tid * 8;
  f32x4 x0 = *(const f32x4*)row;
  f32x4 x1 = *(const f32x4*)(row + 4);
  float ss = x0[0]*x0[0] + x0[1]*x0[1] + x0[2]*x0[2] + x0[3]*x0[3]
           + x1[0]*x1[0] + x1[1]*x1[1] + x1[2]*x1[2] + x1[3]*x1[3];
#pragma unroll
  for (int o = 32; o; o >>= 1) ss += __shfl_xor(ss, o, 64);
  __shared__ float red[4];
  if ((tid & 63) == 0) red[tid >> 6] = ss;
  __syncthreads();
  if (tid == 0) {
    float tot = red[0] + red[1] + red[2] + red[3];
    rnorm[b * H_ + r] = 1.f / fmaxf(sqrtf(tot), 1e-12f);
  }
  u32x4 o;
  o[0] = pk2(x0[0], x0[1]); o[1] = pk2(x0[2], x0[3]);
  o[2] = pk2(x1[0], x1[1]); o[3] = pk2(x1[2], x1[3]);
  *(u32x4*)orow = o;
}

// ---------------------------------------------------------------------------
// column sums (means over padded length 2048) — two stage for parallelism
// ---------------------------------------------------------------------------
__global__ __launch_bounds__(256) void col_sum_part(
    const float* __restrict__ vis, const float* __restrict__ lang,
    float* __restrict__ part) {
  // grid (8, 8, 8): x=h-chunk, y=row-chunk(256), z = b*2+which (which: 0=vis,1=lang)
  const int h = blockIdx.x * 256 + threadIdx.x;
  const int y = blockIdx.y;
  const int which = blockIdx.z & 1;
  const int b = blockIdx.z >> 1;
  const int rows = which ? 2048 : 1024;
  const int r0 = y * 256;
  float s = 0.f;
  if (r0 < rows) {
    const float* p = (which ? lang + (long)b * (2048L * 2048)
                            : vis + (long)b * (1024L * 2048)) + (long)r0 * H_ + h;
#pragma unroll 4
    for (int i = 0; i < 256; ++i) s += p[(long)i * H_];
  }
  part[(((long)which * 4 + b) * 8 + y) * H_ + h] = s;
}

__global__ __launch_bounds__(256) void col_sum_final(
    const float* __restrict__ part, float* __restrict__ vavg,
    float* __restrict__ lavg) {
  // grid (8, 4, 2)
  const int h = blockIdx.x * 256 + threadIdx.x;
  const int b = blockIdx.y;
  const int which = blockIdx.z;
  const float* p = part + (((long)which * 4 + b) * 8) * H_ + h;
  float s = 0.f;
#pragma unroll
  for (int y = 0; y < 8; ++y) s += p[y * H_];
  (which ? lavg : vavg)[b * H_ + h] = s * (1.f / 2048.f);
}

// ---------------------------------------------------------------------------
// bias GEMV: bias[b,h] = sum_{d<2048} avg[b,d] * W[h*4096 + d]   (4 batches/wave)
// ---------------------------------------------------------------------------
__global__ __launch_bounds__(256) void bias_gemv(
    const float* __restrict__ W, const float* __restrict__ avg,
    float* __restrict__ bias) {
  const int lane = threadIdx.x & 63;
  const int wv = threadIdx.x >> 6;
  const int h = blockIdx.x * 4 + wv;
  const float* wrow = W + (long)h * 4096;
  float a0 = 0.f, a1 = 0.f, a2 = 0.f, a3 = 0.f;
#pragma unroll
  for (int i = 0; i < 8; ++i) {
    const int d = i * 256 + lane * 4;
    f32x4 w4 = *(const f32x4*)(wrow + d);
    f32x4 v0 = *(const f32x4*)(avg + 0 * H_ + d);
    f32x4 v1 = *(const f32x4*)(avg + 1 * H_ + d);
    f32x4 v2 = *(const f32x4*)(avg + 2 * H_ + d);
    f32x4 v3 = *(const f32x4*)(avg + 3 * H_ + d);
    a0 += w4[0]*v0[0] + w4[1]*v0[1] + w4[2]*v0[2] + w4[3]*v0[3];
    a1 += w4[0]*v1[0] + w4[1]*v1[1] + w4[2]*v1[2] + w4[3]*v1[3];
    a2 += w4[0]*v2[0] + w4[1]*v2[1] + w4[2]*v2[2] + w4[3]*v2[3];
    a3 += w4[0]*v3[0] + w4[1]*v3[1] + w4[2]*v3[2] + w4[3]*v3[3];
  }
#pragma unroll
  for (int o = 32; o; o >>= 1) {
    a0 += __shfl_xor(a0, o, 64);
    a1 += __shfl_xor(a1, o, 64);
    a2 += __shfl_xor(a2, o, 64);
    a3 += __shfl_xor(a3, o, 64);
  }
  if (lane == 0) {
    bias[0 * H_ + h] = a0; bias[1 * H_ + h] = a1;
    bias[2 * H_ + h] = a2; bias[3 * H_ + h] = a3;
  }
}

// ---------------------------------------------------------------------------
// transpose lang (f32 [b][l][h]) -> lang_T (bf16 [b][h][l])
// ---------------------------------------------------------------------------
__global__ __launch_bounds__(256) void transpose_bf(
    const float* __restrict__ in, unsigned short* __restrict__ out) {
  __shared__ unsigned short tle[64][72];
  const int b = blockIdx.z;
  const int l0 = blockIdx.y * 64, h0 = blockIdx.x * 64;
  const float* inb = in + (long)b * (2048L * 2048);
  unsigned short* outb = out + (long)b * (2048L * 2048);
#pragma unroll
  for (int i = 0; i < 16; ++i) {
    const int idx = i * 256 + threadIdx.x;
    const int r = idx >> 6, c = idx & 63;
    tle[r][c] = f2bf(inb[(long)(l0 + r) * H_ + h0 + c]);
  }
  __syncthreads();
#pragma unroll
  for (int i = 0; i < 16; ++i) {
    const int idx = i * 256 + threadIdx.x;
    const int r = idx >> 6, c = idx & 63;  // r = h-local, c = l-local
    outb[(long)(h0 + r) * H_ + l0 + c] = tle[c][r];
  }
}

// ---------------------------------------------------------------------------
// extract W[:, 2048:4096] as bf16 row-major [h][k]
// ---------------------------------------------------------------------------
__global__ __launch_bounds__(256) void extract_whi(
    const float* __restrict__ Wvl, const float* __restrict__ Wlv,
    unsigned short* __restrict__ WvlHi, unsigned short* __restrict__ WlvHi) {
  const int h = blockIdx.x;
  const int which = blockIdx.y;
  const float* src = (which ? Wlv : Wvl) + (long)h * 4096 + 2048 + threadIdx.x * 8;
  unsigned short* dst = (which ? WlvHi : WvlHi) + (long)h * H_ + threadIdx.x * 8;
  f32x4 x0 = *(const f32x4*)src;
  f32x4 x1 = *(const f32x4*)(src + 4);
  u32x4 o;
  o[0] = pk2(x0[0], x0[1]); o[1] = pk2(x0[2], x0[3]);
  o[2] = pk2(x1[0], x1[1]); o[3] = pk2(x1[2], x1[3]);
  *(u32x4*)dst = o;
}

// ---------------------------------------------------------------------------
// row softmax in place over bf16 [rows][2048]
// ---------------------------------------------------------------------------
__global__ __launch_bounds__(256) void softmax_rows(unsigned short* __restrict__ S) {
  const int tid = threadIdx.x;
  const int lane = tid & 63, wv = tid >> 6;
  unsigned short* rowp = S + (long)blockIdx.x * H_ + tid * 8;
  u32x4 raw = *(const u32x4*)rowp;
  float v[8];
#pragma unroll
  for (int i = 0; i < 4; ++i) {
    v[2 * i]     = bf2f((unsigned short)(raw[i] & 0xFFFFu));
    v[2 * i + 1] = bf2f((unsigned short)(raw[i] >> 16));
  }
  float mx = v[0];
#pragma unroll
  for (int i = 1; i < 8; ++i) mx = fmaxf(mx, v[i]);
#pragma unroll
  for (int o = 32; o; o >>= 1) mx = fmaxf(mx, __shfl_xor(mx, o, 64));
  __shared__ float red[4];
  if (lane == 0) red[wv] = mx;
  __syncthreads();
  const float MX = fmaxf(fmaxf(red[0], red[1]), fmaxf(red[2], red[3]));
  float p[8], s = 0.f;
#pragma unroll
  for (int i = 0; i < 8; ++i) { p[i] = __expf(v[i] - MX); s += p[i]; }
#pragma unroll
  for (int o = 32; o; o >>= 1) s += __shfl_xor(s, o, 64);
  __syncthreads();
  if (lane == 0) red[wv] = s;
  __syncthreads();
  const float inv = 1.f / (red[0] + red[1] + red[2] + red[3]);
  u32x4 o;
#pragma unroll
  for (int i = 0; i < 4; ++i) o[i] = pk2(p[2 * i] * inv, p[2 * i + 1] * inv);
  *(u32x4*)rowp = o;
}

// ---------------------------------------------------------------------------
// NT GEMM (C = A * B^T), A: M x 2048 bf16 row-major, B: 2048 x 2048 bf16
// row-major (N-major, K-contiguous). 128x128 tile, BK=32, 4 waves.
// Triple-buffered LDS + counted vmcnt(8) pipeline (T3/T4), bank-conflict-free
// reads via pre-swizzled global source column kg' = kg ^ ((row>>1)&3) (T2,
// rule #21: linear global_load_lds dest + inverse-swz source + swz read).
// MODE 0: scores (scale rv*rl -> bf16); MODE 1: f32 write (fused);
// MODE 2: sigmoid-gate epilogue.
// ---------------------------------------------------------------------------
struct EpArgs {
  unsigned short* Sout; const float* rv; const float* rl;  // MODE 0
  float* Fout;                                             // MODE 1
  const float* resid; const float* fusedIn; const float* bias; float* Oout;
  long sResid, sFused, sOut;                               // MODE 2
};

#define BAR_ asm volatile("s_barrier" ::: "memory")
#define WAITV_(n) asm volatile("s_waitcnt vmcnt(" #n ")" ::: "memory")

template <int MODE>
__global__ __launch_bounds__(256) void gemm_nt(
    const unsigned short* __restrict__ A, long sA,
    const unsigned short* __restrict__ B, long sB, EpArgs ep) {
  const int tid = threadIdx.x;
  const int lane = tid & 63;
  const int wave = tid >> 6;
  const int b = blockIdx.z;
  const int bm = blockIdx.y << 7;
  const int bn = blockIdx.x << 7;

  // 3 buffers x (128 rows x 32 k) x bf16 = 3 x 8 KB each operand = 48 KB
  __shared__ unsigned short As[3 * 4096];
  __shared__ unsigned short Bs[3 * 4096];

  const unsigned short* Ab = A + (long)b * sA;
  const unsigned short* Bb = B + (long)b * sB;
  const int r0 = tid >> 2;
  // inverse-swizzled source column: slot (row, s) holds global k-group s^((row>>1)&3)
  const int kcS = (((tid & 3) ^ ((tid >> 3) & 3)) << 3);
  const unsigned short* gA = Ab + (long)(bm + r0) * H_ + kcS;
  const unsigned short* gB = Bb + (long)(bn + r0) * H_ + kcS;

  f32x4 acc[4][4];
#pragma unroll
  for (int m = 0; m < 4; ++m)
#pragma unroll
    for (int n = 0; n < 4; ++n) acc[m][n] = (f32x4){0.f, 0.f, 0.f, 0.f};

  const int wr = (wave >> 1) << 6;
  const int wc = (wave & 1) << 6;
  const int row16 = lane & 15;
  const int kg = lane >> 4;
  const int kgs = kg ^ ((lane >> 1) & 3);  // swizzled read k-group

#define STAGE_(kt, buf)                                       \
  do {                                                        \
    const unsigned short* a_ = gA + (kt) * 32;                \
    const unsigned short* b_ = gB + (kt) * 32;                \
    char* la = (char*)As + (buf) * 8192 + wave * 1024;        \
    char* lb = (char*)Bs + (buf) * 8192 + wave * 1024;        \
    GLDS16(a_, la); GLDS16(a_ + 64 * H_, la + 4096);          \
    GLDS16(b_, lb); GLDS16(b_ + 64 * H_, lb + 4096);          \
  } while (0)

#define COMPUTE_(buf)                                                       \
  do {                                                                      \
    const unsigned short* Asb = As + (buf) * 4096;                          \
    const unsigned short* Bsb = Bs + (buf) * 4096;                          \
    short8 af[4], bfv[4];                                                   \
    _Pragma("unroll") for (int m = 0; m < 4; ++m)                           \
        af[m] = *(const short8*)(Asb + (wr + m * 16 + row16) * 32 + kgs * 8); \
    _Pragma("unroll") for (int n = 0; n < 4; ++n)                           \
        bfv[n] = *(const short8*)(Bsb + (wc + n * 16 + row16) * 32 + kgs * 8); \
    __builtin_amdgcn_s_setprio(1);                                          \
    _Pragma("unroll") for (int m = 0; m < 4; ++m)                           \
        _Pragma("unroll") for (int n = 0; n < 4; ++n)                       \
            acc[m][n] = __builtin_amdgcn_mfma_f32_16x16x32_bf16(            \
                af[m], bfv[n], acc[m][n], 0, 0, 0);                         \
    __builtin_amdgcn_s_setprio(0);                                          \
  } while (0)

  // prologue: tiles 0,1,2 in flight (12 loads); wait oldest 4 -> tile 0 ready
  STAGE_(0, 0); STAGE_(1, 1); STAGE_(2, 2);
  WAITV_(8);
  BAR_;
  // steady state: compute kt, barrier (reads done block-wide), restage kt+3,
  // vmcnt(8) -> tile kt+1 landed, barrier.
  for (int k3 = 0; k3 < 60; k3 += 3) {
    COMPUTE_(0); BAR_; STAGE_(k3 + 3, 0); WAITV_(8); BAR_;
    COMPUTE_(1); BAR_; STAGE_(k3 + 4, 1); WAITV_(8); BAR_;
    COMPUTE_(2); BAR_; STAGE_(k3 + 5, 2); WAITV_(8); BAR_;
  }
  COMPUTE_(0); BAR_; STAGE_(63, 0); WAITV_(8); BAR_;  // kt=60
  COMPUTE_(1); BAR_; WAITV_(4); BAR_;                 // kt=61
  COMPUTE_(2); BAR_; WAITV_(0); BAR_;                 // kt=62
  COMPUTE_(0);                                        // kt=63

  // C/D layout: col = lane&15, row = (lane>>4)*4 + j   [verified m89/m91]
  const int cr0 = bm + wr + kg * 4;
  const int cc0 = bn + wc + row16;

  if (MODE == 0) {
    float rvv[4][4], rlv[4];
#pragma unroll
    for (int m = 0; m < 4; ++m)
#pragma unroll
      for (int j = 0; j < 4; ++j) rvv[m][j] = ep.rv[b * H_ + cr0 + m * 16 + j];
#pragma unroll
    for (int n = 0; n < 4; ++n) rlv[n] = ep.rl[b * H_ + cc0 + n * 16];
    unsigned short* Sb = ep.Sout + (long)b * (H_ * (long)H_);
#pragma unroll
    for (int m = 0; m < 4; ++m)
#pragma unroll
      for (int n = 0; n < 4; ++n)
#pragma unroll
        for (int j = 0; j < 4; ++j) {
          const long idx = (long)(cr0 + m * 16 + j) * H_ + cc0 + n * 16;
          Sb[idx] = f2bf(acc[m][n][j] * rvv[m][j] * rlv[n]);
        }
  } else if (MODE == 1) {
    float* Fb = ep.Fout + (long)b * (H_ * (long)H_);
#pragma unroll
    for (int m = 0; m < 4; ++m)
#pragma unroll
      for (int n = 0; n < 4; ++n)
#pragma unroll
        for (int j = 0; j < 4; ++j) {
          const long idx = (long)(cr0 + m * 16 + j) * H_ + cc0 + n * 16;
          Fb[idx] = acc[m][n][j];
        }
  } else {
    const float* Rb = ep.resid + (long)b * ep.sResid;
    const float* Fb = ep.fusedIn + (long)b * ep.sFused;
    float* Ob = ep.Oout + (long)b * ep.sOut;
    float bv[4];
#pragma unroll
    for (int n = 0; n < 4; ++n) bv[n] = ep.bias[b * H_ + cc0 + n * 16];
#pragma unroll
    for (int m = 0; m < 4; ++m)
#pragma unroll
      for (int n = 0; n < 4; ++n)
#pragma unroll
        for (int j = 0; j < 4; ++j) {
          const long idx = (long)(cr0 + m * 16 + j) * H_ + cc0 + n * 16;
          const float x = acc[m][n][j] + bv[n];
          const float g = 1.f / (1.f + __expf(-x));
          Ob[idx] = Rb[idx] + Fb[idx] * g;
        }
  }
#undef STAGE_
#undef COMPUTE_
}

// ---------------------------------------------------------------------------
extern "C" void kernel_launch(void* const* d_in, const int* in_sizes, int n_in,
                              void* d_out, int out_size, void* d_ws,
                              size_t ws_size, hipStream_t stream) {
  (void)in_sizes; (void)n_in; (void)out_size; (void)ws_size;
  const float* vis = (const float*)d_in[0];   // [4,1024,2048]
  const float* lang = (const float*)d_in[1];  // [4,2048,2048]
  const float* Wvl = (const float*)d_in[2];   // [2048,4096]
  const float* Wlv = (const float*)d_in[3];   // [2048,4096]

  // d_out regions: fused | vision_output | language_output
  float* out = (float*)d_out;
  float* fused = out;                      // 16,777,216 f32
  float* vis_out = out + 16777216;         //  8,388,608 f32
  float* lang_out = out + 25165824;        // 16,777,216 f32
  // scratch reuse of not-yet-final output regions:
  unsigned short* S = (unsigned short*)lang_out;     // scores/P bf16 (33.5MB of 67MB)
  unsigned short* langT = (unsigned short*)vis_out;  // lang^T bf16 (33.5MB exact)

  // workspace layout
  char* w = (char*)d_ws;
  unsigned short* vis_bf = (unsigned short*)w;               // [4,2048,2048] bf16 (padded)
  unsigned short* lang_bf = (unsigned short*)(w + 33554432); // [4,2048,2048] bf16
  unsigned short* WvlHi = (unsigned short*)(w + 67108864);   // [2048,2048] bf16
  unsigned short* WlvHi = (unsigned short*)(w + 75497472);   // [2048,2048] bf16
  float* rv      = (float*)(w + 83886080);
  float* rl      = (float*)(w + 83918848);
  float* vavg    = (float*)(w + 83951616);
  float* lavg    = (float*)(w + 83984384);
  float* bias_vl = (float*)(w + 84017152);
  float* bias_lv = (float*)(w + 84049920);
  float* part    = (float*)(w + 84082688);  // 512KB partial col sums

  const long sV = 1024L * 2048, sL = 2048L * 2048, sP = 2048L * 2048;

  prep_rows<<<dim3(2048, 4), 256, 0, stream>>>(vis, sV, vis_bf, sP, rv, 1024);
  prep_rows<<<dim3(2048, 4), 256, 0, stream>>>(lang, sL, lang_bf, sP, rl, 2048);
  col_sum_part<<<dim3(8, 8, 8), 256, 0, stream>>>(vis, lang, part);
  col_sum_final<<<dim3(8, 4, 2), 256, 0, stream>>>(part, vavg, lavg);
  bias_gemv<<<512, 256, 0, stream>>>(Wvl, vavg, bias_vl);
  bias_gemv<<<512, 256, 0, stream>>>(Wlv, lavg, bias_lv);
  transpose_bf<<<dim3(32, 32, 4), 256, 0, stream>>>(lang, langT);
  extract_whi<<<dim3(2048, 2), 256, 0, stream>>>(Wvl, Wlv, WvlHi, WlvHi);

  // GEMM1: scores S[b,v,l] = (vis . lang) * rv * rl  -> bf16
  EpArgs e1 = {};
  e1.Sout = S; e1.rv = rv; e1.rl = rl;
  gemm_nt<0><<<dim3(16, 16, 4), 256, 0, stream>>>(vis_bf, sP, lang_bf, sP, e1);

  softmax_rows<<<8192, 256, 0, stream>>>(S);

  // GEMM2: fused[b,v,h] = P . lang  (B = lang^T, NT form) -> f32
  EpArgs e2 = {};
  e2.Fout = fused;
  gemm_nt<1><<<dim3(16, 16, 4), 256, 0, stream>>>(S, sP, langT, sP, e2);

  // GEMM3: language_output = lang + fused * sigmoid(lang.WvlHi^T + bias_vl)
  EpArgs e3 = {};
  e3.resid = lang; e3.sResid = sL;
  e3.fusedIn = fused; e3.sFused = sP;
  e3.bias = bias_vl; e3.Oout = lang_out; e3.sOut = sL;
  gemm_nt<2><<<dim3(16, 16, 4), 256, 0, stream>>>(lang_bf, sP, WvlHi, 0L, e3);

  // GEMM4: vision_output = vis + fused[:, :1024] * sigmoid(vis.WlvHi^T + bias_lv)
  EpArgs e4 = {};
  e4.resid = vis; e4.sResid = sV;
  e4.fusedIn = fused; e4.sFused = sP;
  e4.bias = bias_lv; e4.Oout = vis_out; e4.sOut = sV;
  gemm_nt<2><<<dim3(16, 8, 4), 256, 0, stream>>>(vis_bf, sP, WlvHi, 0L, e4);
}

// Round 3
// 502.790 us; speedup vs baseline: 1.2252x; 1.1491x over previous
//
#include <hip/hip_runtime.h>

// Problem constants (B=4, V=1024, L=2048, H=2048, TEMP=1, EPS=1e-12)
#define H_ 2048

typedef __attribute__((ext_vector_type(8))) short short8;
typedef __attribute__((ext_vector_type(4))) float f32x4;
typedef __attribute__((ext_vector_type(4))) unsigned int u32x4;

__device__ __forceinline__ unsigned short f2bf(float f) {
  unsigned int u = __builtin_bit_cast(unsigned int, f);
  u += 0x7FFFu + ((u >> 16) & 1u);  // RTNE
  return (unsigned short)(u >> 16);
}
__device__ __forceinline__ float bf2f(unsigned short h) {
  unsigned int u = ((unsigned int)h) << 16;
  return __builtin_bit_cast(float, u);
}
__device__ __forceinline__ unsigned int pk2(float a, float b) {
  return (unsigned int)f2bf(a) | ((unsigned int)f2bf(b) << 16);
}

#define GLDS16(gp, lp)                                                 \
  __builtin_amdgcn_global_load_lds(                                    \
      (const __attribute__((address_space(1))) void*)(gp),             \
      (__attribute__((address_space(3))) void*)(lp), 16, 0, 0)

// ---------------------------------------------------------------------------
// prep: per-row 1/max(||row||,eps) + raw bf16 copy; rows >= validRows -> zeros
// ---------------------------------------------------------------------------
__global__ __launch_bounds__(256) void prep_rows(
    const float* __restrict__ in, long sIn,
    unsigned short* __restrict__ outBf, long sOut,
    float* __restrict__ rnorm, int validRows) {
  const int tid = threadIdx.x;
  const int r = blockIdx.x, b = blockIdx.y;
  unsigned short* orow = outBf + (long)b * sOut + (long)r * H_ + tid * 8;
  if (r >= validRows) {
    *(u32x4*)orow = (u32x4){0u, 0u, 0u, 0u};
    if (tid == 0) rnorm[b * H_ + r] = 0.f;
    return;
  }
  const float* row = in + (long)b * sIn + (long)r * H_ + tid * 8;
  f32x4 x0 = *(const f32x4*)row;
  f32x4 x1 = *(const f32x4*)(row + 4);
  float ss = x0[0]*x0[0] + x0[1]*x0[1] + x0[2]*x0[2] + x0[3]*x0[3]
           + x1[0]*x1[0] + x1[1]*x1[1] + x1[2]*x1[2] + x1[3]*x1[3];
#pragma unroll
  for (int o = 32; o; o >>= 1) ss += __shfl_xor(ss, o, 64);
  __shared__ float red[4];
  if ((tid & 63) == 0) red[tid >> 6] = ss;
  __syncthreads();
  if (tid == 0) {
    float tot = red[0] + red[1] + red[2] + red[3];
    rnorm[b * H_ + r] = 1.f / fmaxf(sqrtf(tot), 1e-12f);
  }
  u32x4 o;
  o[0] = pk2(x0[0], x0[1]); o[1] = pk2(x0[2], x0[3]);
  o[2] = pk2(x1[0], x1[1]); o[3] = pk2(x1[2], x1[3]);
  *(u32x4*)orow = o;
}

// ---------------------------------------------------------------------------
// column sums (means over padded length 2048) — two stage for parallelism
// ---------------------------------------------------------------------------
__global__ __launch_bounds__(256) void col_sum_part(
    const float* __restrict__ vis, const float* __restrict__ lang,
    float* __restrict__ part) {
  const int h = blockIdx.x * 256 + threadIdx.x;
  const int y = blockIdx.y;
  const int which = blockIdx.z & 1;
  const int b = blockIdx.z >> 1;
  const int rows = which ? 2048 : 1024;
  const int r0 = y * 256;
  float s = 0.f;
  if (r0 < rows) {
    const float* p = (which ? lang + (long)b * (2048L * 2048)
                            : vis + (long)b * (1024L * 2048)) + (long)r0 * H_ + h;
#pragma unroll 4
    for (int i = 0; i < 256; ++i) s += p[(long)i * H_];
  }
  part[(((long)which * 4 + b) * 8 + y) * H_ + h] = s;
}

__global__ __launch_bounds__(256) void col_sum_final(
    const float* __restrict__ part, float* __restrict__ vavg,
    float* __restrict__ lavg) {
  const int h = blockIdx.x * 256 + threadIdx.x;
  const int b = blockIdx.y;
  const int which = blockIdx.z;
  const float* p = part + (((long)which * 4 + b) * 8) * H_ + h;
  float s = 0.f;
#pragma unroll
  for (int y = 0; y < 8; ++y) s += p[y * H_];
  (which ? lavg : vavg)[b * H_ + h] = s * (1.f / 2048.f);
}

// ---------------------------------------------------------------------------
// bias GEMV: bias[b,h] = sum_{d<2048} avg[b,d] * W[h*4096 + d]
// ---------------------------------------------------------------------------
__global__ __launch_bounds__(256) void bias_gemv(
    const float* __restrict__ W, const float* __restrict__ avg,
    float* __restrict__ bias) {
  const int lane = threadIdx.x & 63;
  const int wv = threadIdx.x >> 6;
  const int h = blockIdx.x * 4 + wv;
  const float* wrow = W + (long)h * 4096;
  float a0 = 0.f, a1 = 0.f, a2 = 0.f, a3 = 0.f;
#pragma unroll
  for (int i = 0; i < 8; ++i) {
    const int d = i * 256 + lane * 4;
    f32x4 w4 = *(const f32x4*)(wrow + d);
    f32x4 v0 = *(const f32x4*)(avg + 0 * H_ + d);
    f32x4 v1 = *(const f32x4*)(avg + 1 * H_ + d);
    f32x4 v2 = *(const f32x4*)(avg + 2 * H_ + d);
    f32x4 v3 = *(const f32x4*)(avg + 3 * H_ + d);
    a0 += w4[0]*v0[0] + w4[1]*v0[1] + w4[2]*v0[2] + w4[3]*v0[3];
    a1 += w4[0]*v1[0] + w4[1]*v1[1] + w4[2]*v1[2] + w4[3]*v1[3];
    a2 += w4[0]*v2[0] + w4[1]*v2[1] + w4[2]*v2[2] + w4[3]*v2[3];
    a3 += w4[0]*v3[0] + w4[1]*v3[1] + w4[2]*v3[2] + w4[3]*v3[3];
  }
#pragma unroll
  for (int o = 32; o; o >>= 1) {
    a0 += __shfl_xor(a0, o, 64);
    a1 += __shfl_xor(a1, o, 64);
    a2 += __shfl_xor(a2, o, 64);
    a3 += __shfl_xor(a3, o, 64);
  }
  if (lane == 0) {
    bias[0 * H_ + h] = a0; bias[1 * H_ + h] = a1;
    bias[2 * H_ + h] = a2; bias[3 * H_ + h] = a3;
  }
}

// ---------------------------------------------------------------------------
// transpose lang (f32 [b][l][h]) -> lang_T (bf16 [b][h][l])
// ---------------------------------------------------------------------------
__global__ __launch_bounds__(256) void transpose_bf(
    const float* __restrict__ in, unsigned short* __restrict__ out) {
  __shared__ unsigned short tle[64][72];
  const int b = blockIdx.z;
  const int l0 = blockIdx.y * 64, h0 = blockIdx.x * 64;
  const float* inb = in + (long)b * (2048L * 2048);
  unsigned short* outb = out + (long)b * (2048L * 2048);
#pragma unroll
  for (int i = 0; i < 16; ++i) {
    const int idx = i * 256 + threadIdx.x;
    const int r = idx >> 6, c = idx & 63;
    tle[r][c] = f2bf(inb[(long)(l0 + r) * H_ + h0 + c]);
  }
  __syncthreads();
#pragma unroll
  for (int i = 0; i < 16; ++i) {
    const int idx = i * 256 + threadIdx.x;
    const int r = idx >> 6, c = idx & 63;  // r = h-local, c = l-local
    outb[(long)(h0 + r) * H_ + l0 + c] = tle[c][r];
  }
}

// ---------------------------------------------------------------------------
// extract W[:, 2048:4096] as bf16 row-major [h][k]
// ---------------------------------------------------------------------------
__global__ __launch_bounds__(256) void extract_whi(
    const float* __restrict__ Wvl, const float* __restrict__ Wlv,
    unsigned short* __restrict__ WvlHi, unsigned short* __restrict__ WlvHi) {
  const int h = blockIdx.x;
  const int which = blockIdx.y;
  const float* src = (which ? Wlv : Wvl) + (long)h * 4096 + 2048 + threadIdx.x * 8;
  unsigned short* dst = (which ? WlvHi : WvlHi) + (long)h * H_ + threadIdx.x * 8;
  f32x4 x0 = *(const f32x4*)src;
  f32x4 x1 = *(const f32x4*)(src + 4);
  u32x4 o;
  o[0] = pk2(x0[0], x0[1]); o[1] = pk2(x0[2], x0[3]);
  o[2] = pk2(x1[0], x1[1]); o[3] = pk2(x1[2], x1[3]);
  *(u32x4*)dst = o;
}

// ---------------------------------------------------------------------------
// row softmax in place over bf16 [rows][2048]
// ---------------------------------------------------------------------------
__global__ __launch_bounds__(256) void softmax_rows(unsigned short* __restrict__ S) {
  const int tid = threadIdx.x;
  const int lane = tid & 63, wv = tid >> 6;
  unsigned short* rowp = S + (long)blockIdx.x * H_ + tid * 8;
  u32x4 raw = *(const u32x4*)rowp;
  float v[8];
#pragma unroll
  for (int i = 0; i < 4; ++i) {
    v[2 * i]     = bf2f((unsigned short)(raw[i] & 0xFFFFu));
    v[2 * i + 1] = bf2f((unsigned short)(raw[i] >> 16));
  }
  float mx = v[0];
#pragma unroll
  for (int i = 1; i < 8; ++i) mx = fmaxf(mx, v[i]);
#pragma unroll
  for (int o = 32; o; o >>= 1) mx = fmaxf(mx, __shfl_xor(mx, o, 64));
  __shared__ float red[4];
  if (lane == 0) red[wv] = mx;
  __syncthreads();
  const float MX = fmaxf(fmaxf(red[0], red[1]), fmaxf(red[2], red[3]));
  float p[8], s = 0.f;
#pragma unroll
  for (int i = 0; i < 8; ++i) { p[i] = __expf(v[i] - MX); s += p[i]; }
#pragma unroll
  for (int o = 32; o; o >>= 1) s += __shfl_xor(s, o, 64);
  __syncthreads();
  if (lane == 0) red[wv] = s;
  __syncthreads();
  const float inv = 1.f / (red[0] + red[1] + red[2] + red[3]);
  u32x4 o;
#pragma unroll
  for (int i = 0; i < 4; ++i) o[i] = pk2(p[2 * i] * inv, p[2 * i + 1] * inv);
  *(u32x4*)rowp = o;
}

// ---------------------------------------------------------------------------
// NT GEMM (C = A * B^T), 256x256 tile, BK=64, 8 waves (2M x 4N), 8-phase
// schedule (T3+T4+T5), double-buffered 128KB LDS, counted vmcnt(8) (never 0
// in the main loop), XOR LDS swizzle g' = g ^ (row&7) staged via
// inverse-swizzled global source (rule #21), XCD-aware block swizzle (T1).
// WAR-safe by construction: A(t+2) staged at p2 (A reads end at p1 barrier),
// B(t+2) at p3 (B reads end at p2 barrier); t+2 shares buffer parity with t.
// ---------------------------------------------------------------------------
struct EpArgs {
  unsigned short* Sout; const float* rv; const float* rl;  // MODE 0
  float* Fout;                                             // MODE 1
  const float* resid; const float* fusedIn; const float* bias; float* Oout;
  long sResid, sFused, sOut;                               // MODE 2
};

#define BAR_ asm volatile("s_barrier" ::: "memory")
#define WAITV_(n) asm volatile("s_waitcnt vmcnt(" #n ")" ::: "memory")

template <int MODE>
__global__ __launch_bounds__(512, 2) void gemm_nt(
    const unsigned short* __restrict__ A, long sA,
    const unsigned short* __restrict__ B, long sB, EpArgs ep) {
  // LDS: A buf0 [0,16384) | A buf1 [16384,32768) | B buf0 | B buf1 (elems)
  __shared__ unsigned short LDS[65536];  // 128 KB

  const int tid = threadIdx.x;
  const int lane = tid & 63;
  const int wave = tid >> 6;

  // XCD-aware bijective block swizzle (nwg % 8 == 0 for all our grids)
  const int gx = gridDim.x, gy = gridDim.y;
  const int nwg = gx * gy * gridDim.z;
  const int lin = blockIdx.x + gx * (blockIdx.y + gy * blockIdx.z);
  const int swz = (lin & 7) * (nwg >> 3) + (lin >> 3);
  const int bx = swz % gx;
  const int rest = swz / gx;
  const int by = rest % gy;
  const int b = rest / gy;
  const int bm = by << 8;
  const int bn = bx << 8;

  const unsigned short* Ab = A + (long)b * sA;
  const unsigned short* Bb = B + (long)b * sB;

  // --- staging addressing (global_load_lds: linear dest, pre-swz source) ---
  const int srow = tid >> 3;                              // 0..63
  const int colOff = ((tid & 7) ^ (srow & 7)) << 3;       // swizzled k-offset
  const unsigned short* gA0 = Ab + (long)(bm + srow) * H_ + colOff;
  const unsigned short* gA1 = gA0 + 128 * H_;
  const unsigned short* gB0 = Bb + (long)(bn + srow) * H_ + colOff;
  const unsigned short* gB1 = gB0 + 128 * H_;
  const int ldst = wave * 512;  // wave-uniform LDS base (HW adds lane*16B)

#define STAGE_A_(kt, bo)                                          \
  do {                                                            \
    const unsigned short* pa0_ = gA0 + (kt) * 64;                 \
    const unsigned short* pa1_ = gA1 + (kt) * 64;                 \
    GLDS16(pa0_,           &LDS[(bo) + ldst]);                    \
    GLDS16(pa0_ + 64 * H_, &LDS[(bo) + 4096 + ldst]);             \
    GLDS16(pa1_,           &LDS[(bo) + 8192 + ldst]);             \
    GLDS16(pa1_ + 64 * H_, &LDS[(bo) + 12288 + ldst]);            \
  } while (0)
#define STAGE_B_(kt, bo)                                          \
  do {                                                            \
    const unsigned short* pb0_ = gB0 + (kt) * 64;                 \
    const unsigned short* pb1_ = gB1 + (kt) * 64;                 \
    GLDS16(pb0_,           &LDS[(bo) + ldst]);                    \
    GLDS16(pb0_ + 64 * H_, &LDS[(bo) + 4096 + ldst]);             \
    GLDS16(pb1_,           &LDS[(bo) + 8192 + ldst]);             \
    GLDS16(pb1_ + 64 * H_, &LDS[(bo) + 12288 + ldst]);            \
  } while (0)

  // --- fragment addressing (swizzled read) ---
  const int row16 = lane & 15;
  const int kg = lane >> 4;
  const int wr = (wave >> 2) << 7;   // 0 or 128
  const int wc = (wave & 3) << 6;    // 0,64,128,192
  const int sw0 = (kg ^ (row16 & 7)) << 3;
  const int sw1 = ((4 + kg) ^ (row16 & 7)) << 3;
  const int ra = (wr + row16) << 6;
  const int rb = (wc + row16) << 6;

#define RDA_(m, ks) (*(const short8*)&LDS[bufA + ra + (m) * 1024 + ((ks) ? sw1 : sw0)])
#define RDB_(n, ks) (*(const short8*)&LDS[bufB + rb + (n) * 1024 + ((ks) ? sw1 : sw0)])

  f32x4 acc[8][4];
#pragma unroll
  for (int m = 0; m < 8; ++m)
#pragma unroll
    for (int n = 0; n < 4; ++n) acc[m][n] = (f32x4){0.f, 0.f, 0.f, 0.f};
  short8 aF[8][2], bF[4][2];

#define MF16_(MLO, NLO)                                                      \
  do {                                                                       \
    __builtin_amdgcn_s_setprio(1);                                           \
    _Pragma("unroll") for (int m_ = 0; m_ < 4; ++m_)                         \
    _Pragma("unroll") for (int n_ = 0; n_ < 2; ++n_) {                       \
      acc[(MLO) + m_][(NLO) + n_] = __builtin_amdgcn_mfma_f32_16x16x32_bf16( \
          aF[(MLO) + m_][0], bF[(NLO) + n_][0],                              \
          acc[(MLO) + m_][(NLO) + n_], 0, 0, 0);                             \
      acc[(MLO) + m_][(NLO) + n_] = __builtin_amdgcn_mfma_f32_16x16x32_bf16( \
          aF[(MLO) + m_][1], bF[(NLO) + n_][1],                              \
          acc[(MLO) + m_][(NLO) + n_], 0, 0, 0);                             \
    }                                                                        \
    __builtin_amdgcn_s_setprio(0);                                           \
  } while (0)

#define ITER_(t, DOSTAGE, WV)                                               \
  do {                                                                      \
    const int bufA = ((t) & 1) << 14;                                       \
    const int bufB = 32768 + (((t) & 1) << 14);                             \
    /* p0: read A m0-3 + B n0-1, quad(0,0) */                               \
    _Pragma("unroll") for (int m_ = 0; m_ < 4; ++m_) {                      \
      aF[m_][0] = RDA_(m_, 0); aF[m_][1] = RDA_(m_, 1);                     \
    }                                                                       \
    _Pragma("unroll") for (int n_ = 0; n_ < 2; ++n_) {                      \
      bF[n_][0] = RDB_(n_, 0); bF[n_][1] = RDB_(n_, 1);                     \
    }                                                                       \
    BAR_; MF16_(0, 0); BAR_;                                                \
    /* p1: read A m4-7, quad(1,0) */                                        \
    _Pragma("unroll") for (int m_ = 0; m_ < 4; ++m_) {                      \
      aF[4 + m_][0] = RDA_(4 + m_, 0); aF[4 + m_][1] = RDA_(4 + m_, 1);     \
    }                                                                       \
    BAR_; MF16_(4, 0); BAR_;                                                \
    /* p2: read B n2-3, stage A(t+2), quad(0,1) */                          \
    _Pragma("unroll") for (int n_ = 0; n_ < 2; ++n_) {                      \
      bF[2 + n_][0] = RDB_(2 + n_, 0); bF[2 + n_][1] = RDB_(2 + n_, 1);     \
    }                                                                       \
    if (DOSTAGE) STAGE_A_((t) + 2, bufA);                                   \
    BAR_; MF16_(0, 2); BAR_;                                                \
    /* p3: stage B(t+2), counted wait, quad(1,1) */                         \
    if (DOSTAGE) STAGE_B_((t) + 2, bufB);                                   \
    WV; BAR_; MF16_(4, 2); BAR_;                                            \
  } while (0)

  // prologue: tiles 0 (buf0) and 1 (buf1); wait tile 0 landed (8 newest = t1)
  STAGE_A_(0, 0); STAGE_B_(0, 32768);
  STAGE_A_(1, 16384); STAGE_B_(1, 32768 + 16384);
  WAITV_(8);
  BAR_;

  for (int t = 0; t < 30; ++t) { ITER_(t, 1, WAITV_(8)); }
  ITER_(30, 0, WAITV_(0));
  ITER_(31, 0, (void)0);

  // C/D layout: col = lane&15, row = (lane>>4)*4 + j   [verified m89/m91]
  const int cr0 = bm + wr + kg * 4;
  const int cc0 = bn + wc + row16;

  if (MODE == 0) {
    float rvv[8][4], rlv[4];
#pragma unroll
    for (int m = 0; m < 8; ++m)
#pragma unroll
      for (int j = 0; j < 4; ++j) rvv[m][j] = ep.rv[b * H_ + cr0 + m * 16 + j];
#pragma unroll
    for (int n = 0; n < 4; ++n) rlv[n] = ep.rl[b * H_ + cc0 + n * 16];
    unsigned short* Sb = ep.Sout + (long)b * (H_ * (long)H_);
#pragma unroll
    for (int m = 0; m < 8; ++m)
#pragma unroll
      for (int n = 0; n < 4; ++n)
#pragma unroll
        for (int j = 0; j < 4; ++j) {
          const long idx = (long)(cr0 + m * 16 + j) * H_ + cc0 + n * 16;
          Sb[idx] = f2bf(acc[m][n][j] * rvv[m][j] * rlv[n]);
        }
  } else if (MODE == 1) {
    float* Fb = ep.Fout + (long)b * (H_ * (long)H_);
#pragma unroll
    for (int m = 0; m < 8; ++m)
#pragma unroll
      for (int n = 0; n < 4; ++n)
#pragma unroll
        for (int j = 0; j < 4; ++j) {
          const long idx = (long)(cr0 + m * 16 + j) * H_ + cc0 + n * 16;
          Fb[idx] = acc[m][n][j];
        }
  } else {
    const float* Rb = ep.resid + (long)b * ep.sResid;
    const float* Fb = ep.fusedIn + (long)b * ep.sFused;
    float* Ob = ep.Oout + (long)b * ep.sOut;
    float bv[4];
#pragma unroll
    for (int n = 0; n < 4; ++n) bv[n] = ep.bias[b * H_ + cc0 + n * 16];
#pragma unroll
    for (int m = 0; m < 8; ++m)
#pragma unroll
      for (int n = 0; n < 4; ++n)
#pragma unroll
        for (int j = 0; j < 4; ++j) {
          const long idx = (long)(cr0 + m * 16 + j) * H_ + cc0 + n * 16;
          const float x = acc[m][n][j] + bv[n];
          const float g = 1.f / (1.f + __expf(-x));
          Ob[idx] = Rb[idx] + Fb[idx] * g;
        }
  }
#undef STAGE_A_
#undef STAGE_B_
#undef RDA_
#undef RDB_
#undef MF16_
#undef ITER_
}

// ---------------------------------------------------------------------------
extern "C" void kernel_launch(void* const* d_in, const int* in_sizes, int n_in,
                              void* d_out, int out_size, void* d_ws,
                              size_t ws_size, hipStream_t stream) {
  (void)in_sizes; (void)n_in; (void)out_size; (void)ws_size;
  const float* vis = (const float*)d_in[0];   // [4,1024,2048]
  const float* lang = (const float*)d_in[1];  // [4,2048,2048]
  const float* Wvl = (const float*)d_in[2];   // [2048,4096]
  const float* Wlv = (const float*)d_in[3];   // [2048,4096]

  // d_out regions: fused | vision_output | language_output
  float* out = (float*)d_out;
  float* fused = out;                      // 16,777,216 f32
  float* vis_out = out + 16777216;         //  8,388,608 f32
  float* lang_out = out + 25165824;        // 16,777,216 f32
  // scratch reuse of not-yet-final output regions:
  unsigned short* S = (unsigned short*)lang_out;     // scores/P bf16
  unsigned short* langT = (unsigned short*)vis_out;  // lang^T bf16

  // workspace layout
  char* w = (char*)d_ws;
  unsigned short* vis_bf = (unsigned short*)w;               // [4,2048,2048] bf16 (padded)
  unsigned short* lang_bf = (unsigned short*)(w + 33554432); // [4,2048,2048] bf16
  unsigned short* WvlHi = (unsigned short*)(w + 67108864);   // [2048,2048] bf16
  unsigned short* WlvHi = (unsigned short*)(w + 75497472);   // [2048,2048] bf16
  float* rv      = (float*)(w + 83886080);
  float* rl      = (float*)(w + 83918848);
  float* vavg    = (float*)(w + 83951616);
  float* lavg    = (float*)(w + 83984384);
  float* bias_vl = (float*)(w + 84017152);
  float* bias_lv = (float*)(w + 84049920);
  float* part    = (float*)(w + 84082688);  // 512KB partial col sums

  const long sV = 1024L * 2048, sL = 2048L * 2048, sP = 2048L * 2048;

  prep_rows<<<dim3(2048, 4), 256, 0, stream>>>(vis, sV, vis_bf, sP, rv, 1024);
  prep_rows<<<dim3(2048, 4), 256, 0, stream>>>(lang, sL, lang_bf, sP, rl, 2048);
  col_sum_part<<<dim3(8, 8, 8), 256, 0, stream>>>(vis, lang, part);
  col_sum_final<<<dim3(8, 4, 2), 256, 0, stream>>>(part, vavg, lavg);
  bias_gemv<<<512, 256, 0, stream>>>(Wvl, vavg, bias_vl);
  bias_gemv<<<512, 256, 0, stream>>>(Wlv, lavg, bias_lv);
  transpose_bf<<<dim3(32, 32, 4), 256, 0, stream>>>(lang, langT);
  extract_whi<<<dim3(2048, 2), 256, 0, stream>>>(Wvl, Wlv, WvlHi, WlvHi);

  // GEMM1: scores S[b,v,l] = (vis . lang) * rv * rl  -> bf16
  EpArgs e1 = {};
  e1.Sout = S; e1.rv = rv; e1.rl = rl;
  gemm_nt<0><<<dim3(8, 8, 4), 512, 0, stream>>>(vis_bf, sP, lang_bf, sP, e1);

  softmax_rows<<<8192, 256, 0, stream>>>(S);

  // GEMM2: fused[b,v,h] = P . lang  (B = lang^T, NT form) -> f32
  EpArgs e2 = {};
  e2.Fout = fused;
  gemm_nt<1><<<dim3(8, 8, 4), 512, 0, stream>>>(S, sP, langT, sP, e2);

  // GEMM3: language_output = lang + fused * sigmoid(lang.WvlHi^T + bias_vl)
  EpArgs e3 = {};
  e3.resid = lang; e3.sResid = sL;
  e3.fusedIn = fused; e3.sFused = sP;
  e3.bias = bias_vl; e3.Oout = lang_out; e3.sOut = sL;
  gemm_nt<2><<<dim3(8, 8, 4), 512, 0, stream>>>(lang_bf, sP, WvlHi, 0L, e3);

  // GEMM4: vision_output = vis + fused[:, :1024] * sigmoid(vis.WlvHi^T + bias_lv)
  EpArgs e4 = {};
  e4.resid = vis; e4.sResid = sV;
  e4.fusedIn = fused; e4.sFused = sP;
  e4.bias = bias_lv; e4.Oout = vis_out; e4.sOut = sV;
  gemm_nt<2><<<dim3(8, 4, 4), 512, 0, stream>>>(vis_bf, sP, WlvHi, 0L, e4);
}